// Round 1
// baseline (8919.395 us; speedup 1.0000x reference)
//
#include <hip/hip_runtime.h>
#include <stdint.h>

#define TOK 4096
#define HDIM 512
#define GR 2560          // 5*HDIM
#define TS 4095          // sequential steps (child rows)

typedef __bf16 bf16x8 __attribute__((ext_vector_type(8)));
typedef float f32x4 __attribute__((ext_vector_type(4)));
typedef unsigned long long u64;
typedef unsigned short u16;
typedef unsigned int u32;

__device__ __forceinline__ u16 f2b(float x){
  u32 u = __float_as_uint(x);
  return (u16)((u + 0x7fffu + ((u >> 16) & 1u)) >> 16);
}
__device__ __forceinline__ float b2f(u16 h){ return __uint_as_float(((u32)h) << 16); }

// ---------- f32 -> bf16 convert (grid-stride) ----------
__global__ void k_f2b(const float* __restrict__ in, u16* __restrict__ out, int n){
  for (int i = blockIdx.x*256 + threadIdx.x; i < n; i += gridDim.x*256)
    out[i] = f2b(in[i]);
}

// ---------- child = bf16(hidden[1:]) with zero pad row ----------
__global__ void k_child(const float* __restrict__ hidden, u16* __restrict__ child){
  int i = blockIdx.x*256 + threadIdx.x;
  if (i >= TOK*HDIM) return;
  child[i] = (i < TS*HDIM) ? f2b(hidden[i + HDIM]) : (u16)0;
}

// ---------- bxh = bx + bh ----------
__global__ void k_bias(const float* __restrict__ a, const float* __restrict__ b,
                       float* __restrict__ o, int n){
  int i = blockIdx.x*256 + threadIdx.x;
  if (i < n) o[i] = a[i] + b[i];
}

// ---------- init: zero out row 0, reset h-exchange tags (every launch!) ----------
__global__ void k_init(float* __restrict__ out0, u64* __restrict__ hx){
  int i = blockIdx.x*256 + threadIdx.x;
  if (i < 1024) out0[i] = 0.f;
  if (i < 2048) hx[i] = ((i >> 9) & 1) ? (0xFFFFFFFFull << 32) : 0ull; // par1=BAD, par0=tag0/val0
}

// ---------- el/er: per-head 64-dim dots ----------
__global__ __launch_bounds__(256) void k_eler(const float* __restrict__ basic,
    const float* __restrict__ wl, const float* __restrict__ wr,
    float* __restrict__ el, float* __restrict__ er){
  int h = blockIdx.x;
  int i = blockIdx.y*256 + threadIdx.x;
  const float4* bp = (const float4*)(basic + (size_t)i*HDIM + h*64);
  const float4* wl4 = (const float4*)wl;
  const float4* wr4 = (const float4*)wr;
  float e1 = 0.f, e2 = 0.f;
  #pragma unroll
  for (int q = 0; q < 16; ++q){
    float4 v = bp[q], a = wl4[q], b = wr4[q];
    e1 += v.x*a.x + v.y*a.y + v.z*a.z + v.w*a.w;
    e2 += v.x*b.x + v.y*b.y + v.z*b.z + v.w*b.w;
  }
  el[h*TOK + i] = e1;
  er[h*TOK + i] = e2;
}

// ---------- attention: flash-style, 64 i-rows per wg ----------
__global__ __launch_bounds__(256) void k_attn(const float* __restrict__ basic,
    const float* __restrict__ el, const float* __restrict__ er,
    const float* __restrict__ abp, float* __restrict__ hidden){
  __shared__ __align__(16) float tf[64*64];
  __shared__ __align__(16) float wb[64*64];   // wb[j][i]
  __shared__ float els[64];
  __shared__ float den4[4*64];
  __shared__ float dens[64];
  int h = blockIdx.y, i0 = blockIdx.x*64;
  int t = threadIdx.x;
  if (t < 64) els[t] = el[h*TOK + i0 + t] + abp[0];
  int iA = t & 63, jg = t >> 6;     // phase A: thread = (i, j-quarter)
  int dg = t & 15, ig = t >> 4;     // phase B: thread = (4 d's, 4 i's)
  float acc[16];
  #pragma unroll
  for (int q = 0; q < 16; ++q) acc[q] = 0.f;
  float dsum = 0.f;
  const float* erh = er + h*TOK;
  __syncthreads();
  float elsv = els[iA];
  for (int j0 = 0; j0 < TOK; j0 += 64){
    __syncthreads();  // protect tf/wb from previous iteration readers
    #pragma unroll
    for (int q = 0; q < 4; ++q){
      int f4 = q*256 + t, j = f4 >> 4, d4 = f4 & 15;
      *(float4*)&tf[j*64 + d4*4] = *(const float4*)&basic[(size_t)(j0+j)*HDIM + h*64 + d4*4];
    }
    #pragma unroll
    for (int q = 0; q < 16; ++q){
      int jj = jg*16 + q;
      float e = elsv + erh[j0 + jj];
      e = e > 0.f ? e : 0.01f*e;
      float wv = __expf(e);
      wb[jj*64 + iA] = wv;          // lanes i-consecutive: conflict-free
      dsum += wv;
    }
    __syncthreads();
    #pragma unroll 4
    for (int jj = 0; jj < 64; ++jj){
      float4 tv = *(const float4*)&tf[jj*64 + dg*4];  // 16 distinct b128 + broadcast: free
      float w0 = wb[jj*64 + ig*4 + 0];                 // wave-uniform: broadcast
      float w1 = wb[jj*64 + ig*4 + 1];
      float w2 = wb[jj*64 + ig*4 + 2];
      float w3 = wb[jj*64 + ig*4 + 3];
      acc[0] += w0*tv.x; acc[1] += w0*tv.y; acc[2] += w0*tv.z; acc[3] += w0*tv.w;
      acc[4] += w1*tv.x; acc[5] += w1*tv.y; acc[6] += w1*tv.z; acc[7] += w1*tv.w;
      acc[8] += w2*tv.x; acc[9] += w2*tv.y; acc[10]+= w2*tv.z; acc[11]+= w2*tv.w;
      acc[12]+= w3*tv.x; acc[13]+= w3*tv.y; acc[14]+= w3*tv.z; acc[15]+= w3*tv.w;
    }
  }
  den4[jg*64 + iA] = dsum;
  __syncthreads();
  if (t < 64) dens[t] = 1.f/(den4[t] + den4[64+t] + den4[128+t] + den4[192+t]);
  __syncthreads();
  #pragma unroll
  for (int ii = 0; ii < 4; ++ii){
    int i = ig*4 + ii;
    float rr = dens[i];
    size_t ob = (size_t)(i0+i)*HDIM + h*64 + dg*4;
    float4 bv = *(const float4*)&basic[ob];
    float4 ov;
    ov.x = bv.x + acc[ii*4+0]*rr;
    ov.y = bv.y + acc[ii*4+1]*rr;
    ov.z = bv.z + acc[ii*4+2]*rr;
    ov.w = bv.w + acc[ii*4+3]*rr;
    *(float4*)&hidden[ob] = ov;
  }
}

// ---------- bf16 MFMA GEMM: C(MrxN) = A(Mx512) @ B(Nx512)^T + bias ----------
template<int OUT_BF16>
__global__ __launch_bounds__(256) void k_gemm(const u16* __restrict__ A,
    const u16* __restrict__ B, void* __restrict__ C, const float* __restrict__ bias,
    int Mr, int Nn){
  __shared__ __align__(16) u16 Al[128*32];
  __shared__ __align__(16) u16 Bl[128*32];
  int tid = threadIdx.x;
  int wave = tid >> 6, lane = tid & 63;
  int m0 = blockIdx.y*128, n0 = blockIdx.x*128;
  int wm = wave >> 1, wn = wave & 1;
  f32x4 acc[4][4];
  #pragma unroll
  for (int a = 0; a < 4; ++a)
    #pragma unroll
    for (int b = 0; b < 4; ++b) acc[a][b] = (f32x4){0.f,0.f,0.f,0.f};
  int srow = lane >> 2;
  int kc = (lane & 3)*8;
  for (int k0 = 0; k0 < 512; k0 += 32){
    __syncthreads();
    #pragma unroll
    for (int n = 0; n < 2; ++n){
      int chunk = n*4 + wave;
      int row = chunk*16 + srow;
      const u16* ga = A + (size_t)(m0+row)*512 + k0 + kc;
      const u16* gb = B + (size_t)(n0+row)*512 + k0 + kc;
      __builtin_amdgcn_global_load_lds((const __attribute__((address_space(1))) void*)ga,
        (__attribute__((address_space(3))) void*)&Al[chunk*512], 16, 0, 0);
      __builtin_amdgcn_global_load_lds((const __attribute__((address_space(1))) void*)gb,
        (__attribute__((address_space(3))) void*)&Bl[chunk*512], 16, 0, 0);
    }
    __syncthreads();
    bf16x8 af[4], bfr[4];
    #pragma unroll
    for (int fm = 0; fm < 4; ++fm)
      af[fm] = *(const bf16x8*)&Al[(wm*64 + fm*16 + (lane&15))*32 + (lane>>4)*8];
    #pragma unroll
    for (int fn = 0; fn < 4; ++fn)
      bfr[fn] = *(const bf16x8*)&Bl[(wn*64 + fn*16 + (lane&15))*32 + (lane>>4)*8];
    #pragma unroll
    for (int fm = 0; fm < 4; ++fm)
      #pragma unroll
      for (int fn = 0; fn < 4; ++fn)
        acc[fm][fn] = __builtin_amdgcn_mfma_f32_16x16x32_bf16(af[fm], bfr[fn], acc[fm][fn], 0, 0, 0);
  }
  float* Cf = (float*)C;
  u16* Cb = (u16*)C;
  #pragma unroll
  for (int fn = 0; fn < 4; ++fn){
    int col = n0 + wn*64 + fn*16 + (lane & 15);
    float bv = bias ? bias[col] : 0.f;
    #pragma unroll
    for (int fm = 0; fm < 4; ++fm){
      #pragma unroll
      for (int rg = 0; rg < 4; ++rg){
        int m = m0 + wm*64 + fm*16 + (lane>>4)*4 + rg;   // C/D: col=lane&15, row=(lane>>4)*4+reg
        if (m < Mr){
          float v = acc[fm][fn][rg] + bv;
          if (OUT_BF16) Cb[(size_t)m*Nn + col] = f2b(v);
          else          Cf[(size_t)m*Nn + col] = v;
        }
      }
    }
  }
}

// ---------- the sequential scan: 64 wgs/direction, Wh rows in registers,
// h exchanged via tagged u64 atomics (tag,value atomic in one word) ----------
__global__ __launch_bounds__(320) void k_scan(
    const float* __restrict__ Wh_f, const float* __restrict__ Wh_b,
    const u16* __restrict__ gxb_f, const u16* __restrict__ gxb_b,
    const u16* __restrict__ px_f, const u16* __restrict__ px_b,
    u64* __restrict__ hx, float* __restrict__ out){
  int wg = blockIdx.x;
  int dir = wg & 1, sl = wg >> 1;   // 64 slices per direction
  int mb = sl*8;                    // this wg owns hidden indices [mb, mb+8)
  int tid = threadIdx.x;
  int rr = tid >> 3, s8 = tid & 7;  // 40 rows x 8 col-chunks
  int gj = rr >> 3, mm = rr & 7;    // gate j (i,o,f,u,r), local m
  int grow = gj*512 + mb + mm;      // global gate-row in [0,2560)
  const float* Wh = dir ? Wh_b : Wh_f;
  const u16* gxb = dir ? gxb_b : gxb_f;
  const u16* px  = dir ? px_b  : px_f;
  u64* hxd = hx + dir*1024;         // [2 parity][512]
  __shared__ __align__(16) float hld[8*72];  // stride 72: 16B-aligned + conflict-free chunks
  __shared__ float gbuf[40];
  float wreg[64];
  {
    const float* wrow = Wh + (size_t)grow*512 + s8*64;
    #pragma unroll
    for (int k = 0; k < 64; ++k) wreg[k] = wrow[k];
  }
  float c = 0.f;
  for (int t = 0; t < TS; ++t){
    int trow = dir ? (4094 - t) : t;
    float gval = 0.f, pxv = 0.f;
    if (s8 == 0) gval = b2f(gxb[(size_t)trow*GR + grow]);      // prefetch (independent of h)
    if (tid < 8) pxv = b2f(px[(size_t)trow*HDIM + mb + tid]);
    { // stage h: spin until tag==t, single round-trip fused poll+load
      u64* src = hxd + (t & 1)*512;
      u64 v = __hip_atomic_load(&src[tid], __ATOMIC_RELAXED, __HIP_MEMORY_SCOPE_AGENT);
      while ((u32)(v >> 32) != (u32)t){
        __builtin_amdgcn_s_sleep(1);
        v = __hip_atomic_load(&src[tid], __ATOMIC_RELAXED, __HIP_MEMORY_SCOPE_AGENT);
      }
      hld[(tid >> 6)*72 + (tid & 63)] = __uint_as_float((u32)v);
      if (tid < 192){
        int s2 = tid + 320;
        v = __hip_atomic_load(&src[s2], __ATOMIC_RELAXED, __HIP_MEMORY_SCOPE_AGENT);
        while ((u32)(v >> 32) != (u32)t){
          __builtin_amdgcn_s_sleep(1);
          v = __hip_atomic_load(&src[s2], __ATOMIC_RELAXED, __HIP_MEMORY_SCOPE_AGENT);
        }
        hld[(s2 >> 6)*72 + (s2 & 63)] = __uint_as_float((u32)v);
      }
    }
    __syncthreads();
    // matvec slice: 64 MACs/thread, weights in VGPRs, h from LDS
    float acc = 0.f;
    const float4* hp4 = (const float4*)&hld[s8*72];
    #pragma unroll
    for (int q = 0; q < 16; ++q){
      float4 hv = hp4[q];
      acc += wreg[q*4+0]*hv.x + wreg[q*4+1]*hv.y + wreg[q*4+2]*hv.z + wreg[q*4+3]*hv.w;
    }
    acc += __shfl_xor(acc, 1);
    acc += __shfl_xor(acc, 2);
    acc += __shfl_xor(acc, 4);
    if (s8 == 0) gbuf[rr] = acc + gval;
    __syncthreads();
    if (tid < 8){
      float gi = gbuf[tid], go = gbuf[8+tid], gf = gbuf[16+tid], gu = gbuf[24+tid], grt = gbuf[32+tid];
      float si = 1.f/(1.f + __expf(-gi));
      float so = 1.f/(1.f + __expf(-go));
      float sf = 1.f/(1.f + __expf(-gf));
      float sr = 1.f/(1.f + __expf(-grt));
      float tu = tanhf(gu);
      c = si*tu + sf*c;
      float hh = so*tanhf(c);
      float hf = sr*hh + (1.f - sr)*pxv;
      int orow = dir ? (4095 - t) : (t + 1);
      out[(size_t)orow*1024 + dir*512 + mb + tid] = hf;
      u64 pv = (((u64)(u32)(t+1)) << 32) | (u64)__float_as_uint(hf);
      __hip_atomic_store(&hxd[((t+1) & 1)*512 + mb + tid], pv,
                         __ATOMIC_RELAXED, __HIP_MEMORY_SCOPE_AGENT);
    }
  }
}

extern "C" void kernel_launch(void* const* d_in, const int* in_sizes, int n_in,
                              void* d_out, int out_size, void* d_ws, size_t ws_size,
                              hipStream_t stream){
  const float* features = (const float*)d_in[0];
  const float* Wr   = (const float*)d_in[1];
  const float* wl   = (const float*)d_in[2];
  const float* wr   = (const float*)d_in[3];
  const float* ab   = (const float*)d_in[4];
  const float* Wx_f = (const float*)d_in[5];
  const float* bx_f = (const float*)d_in[6];
  const float* Wh_f = (const float*)d_in[7];
  const float* bh_f = (const float*)d_in[8];
  const float* Px_f = (const float*)d_in[9];
  const float* pb_f = (const float*)d_in[10];
  const float* Wx_b = (const float*)d_in[11];
  const float* bx_b = (const float*)d_in[12];
  const float* Wh_b = (const float*)d_in[13];
  const float* bh_b = (const float*)d_in[14];
  const float* Px_b = (const float*)d_in[15];
  const float* pb_b = (const float*)d_in[16];
  float* out = (float*)d_out;

  size_t off = 0;
  auto alloc = [&](size_t b)->void*{ void* p = (char*)d_ws + off; off += (b + 255) & ~(size_t)255; return p; };
  u16* feat_b  = (u16*)alloc((size_t)TOK*HDIM*2);
  u16* Wr_b    = (u16*)alloc((size_t)HDIM*HDIM*2);
  u16* Wxf_b   = (u16*)alloc((size_t)GR*HDIM*2);
  u16* Wxb_b   = (u16*)alloc((size_t)GR*HDIM*2);
  u16* Pxf_b   = (u16*)alloc((size_t)HDIM*HDIM*2);
  u16* Pxb_b   = (u16*)alloc((size_t)HDIM*HDIM*2);
  float* bxh_f = (float*)alloc((size_t)GR*4);
  float* bxh_b = (float*)alloc((size_t)GR*4);
  float* basic = (float*)alloc((size_t)TOK*HDIM*4);
  float* el    = (float*)alloc((size_t)8*TOK*4);
  float* er    = (float*)alloc((size_t)8*TOK*4);
  float* hidden= (float*)alloc((size_t)TOK*HDIM*4);
  u16* child_b = (u16*)alloc((size_t)TOK*HDIM*2);
  u16* gxbf    = (u16*)alloc((size_t)TOK*GR*2);
  u16* gxbb    = (u16*)alloc((size_t)TOK*GR*2);
  u16* pxf     = (u16*)alloc((size_t)TOK*HDIM*2);
  u16* pxb     = (u16*)alloc((size_t)TOK*HDIM*2);
  u64* hx      = (u64*)alloc((size_t)2*2*512*8);

  auto cvt = [&](const float* src, u16* dst, int n){
    int nb = (n + 255)/256; if (nb > 2048) nb = 2048;
    k_f2b<<<nb, 256, 0, stream>>>(src, dst, n);
  };
  cvt(features, feat_b, TOK*HDIM);
  cvt(Wr, Wr_b, HDIM*HDIM);
  cvt(Wx_f, Wxf_b, GR*HDIM);
  cvt(Wx_b, Wxb_b, GR*HDIM);
  cvt(Px_f, Pxf_b, HDIM*HDIM);
  cvt(Px_b, Pxb_b, HDIM*HDIM);
  k_bias<<<10, 256, 0, stream>>>(bx_f, bh_f, bxh_f, GR);
  k_bias<<<10, 256, 0, stream>>>(bx_b, bh_b, bxh_b, GR);
  k_init<<<8, 256, 0, stream>>>(out, hx);

  k_gemm<0><<<dim3(4,32), 256, 0, stream>>>(feat_b, Wr_b, basic, nullptr, 4096, HDIM);
  k_eler<<<dim3(8,16), 256, 0, stream>>>(basic, wl, wr, el, er);
  k_attn<<<dim3(64,8), 256, 0, stream>>>(basic, el, er, ab, hidden);
  k_child<<<8192, 256, 0, stream>>>(hidden, child_b);

  k_gemm<1><<<dim3(20,32), 256, 0, stream>>>(child_b, Wxf_b, gxbf, bxh_f, TS, GR);
  k_gemm<1><<<dim3(20,32), 256, 0, stream>>>(child_b, Wxb_b, gxbb, bxh_b, TS, GR);
  k_gemm<1><<<dim3(4,32),  256, 0, stream>>>(child_b, Pxf_b, pxf, pb_f, TS, HDIM);
  k_gemm<1><<<dim3(4,32),  256, 0, stream>>>(child_b, Pxb_b, pxb, pb_b, TS, HDIM);

  k_scan<<<128, 320, 0, stream>>>(Wh_f, Wh_b, gxbf, gxbb, pxf, pxb, hx, out);
}

// Round 2
// 7130.135 us; speedup vs baseline: 1.2509x; 1.2509x over previous
//
#include <hip/hip_runtime.h>
#include <stdint.h>

#define TOK 4096
#define HDIM 512
#define GR 2560          // 5*HDIM
#define TS 4095          // sequential steps (child rows)

typedef __bf16 bf16x8 __attribute__((ext_vector_type(8)));
typedef float f32x4 __attribute__((ext_vector_type(4)));
typedef unsigned long long u64;
typedef unsigned short u16;
typedef unsigned int u32;

__device__ __forceinline__ u16 f2b(float x){
  u32 u = __float_as_uint(x);
  return (u16)((u + 0x7fffu + ((u >> 16) & 1u)) >> 16);
}
__device__ __forceinline__ float b2f(u16 h){ return __uint_as_float(((u32)h) << 16); }

__device__ __forceinline__ float sigf(float x){ return 1.f/(1.f + __expf(-x)); }
__device__ __forceinline__ float tanhfast(float x){
  float e = __expf(2.f*x);            // saturates correctly at +-inf
  return 1.f - 2.f/(e + 1.f);
}

// ---------- f32 -> bf16 convert (grid-stride) ----------
__global__ void k_f2b(const float* __restrict__ in, u16* __restrict__ out, int n){
  for (int i = blockIdx.x*256 + threadIdx.x; i < n; i += gridDim.x*256)
    out[i] = f2b(in[i]);
}

// ---------- child = bf16(hidden[1:]) with zero pad row ----------
__global__ void k_child(const float* __restrict__ hidden, u16* __restrict__ child){
  int i = blockIdx.x*256 + threadIdx.x;
  if (i >= TOK*HDIM) return;
  child[i] = (i < TS*HDIM) ? f2b(hidden[i + HDIM]) : (u16)0;
}

// ---------- bxh = bx + bh ----------
__global__ void k_bias(const float* __restrict__ a, const float* __restrict__ b,
                       float* __restrict__ o, int n){
  int i = blockIdx.x*256 + threadIdx.x;
  if (i < n) o[i] = a[i] + b[i];
}

// ---------- init: zero out row 0, reset h-exchange tags (every launch!) ----------
__global__ void k_init(float* __restrict__ out0, u64* __restrict__ hx){
  int i = blockIdx.x*256 + threadIdx.x;
  if (i < 1024) out0[i] = 0.f;
  if (i < 2048) hx[i] = ((i >> 9) & 1) ? (0xFFFFFFFFull << 32) : 0ull; // par1=BAD, par0=tag0/val0
}

// ---------- el/er: per-head 64-dim dots ----------
__global__ __launch_bounds__(256) void k_eler(const float* __restrict__ basic,
    const float* __restrict__ wl, const float* __restrict__ wr,
    float* __restrict__ el, float* __restrict__ er){
  int h = blockIdx.x;
  int i = blockIdx.y*256 + threadIdx.x;
  const float4* bp = (const float4*)(basic + (size_t)i*HDIM + h*64);
  const float4* wl4 = (const float4*)wl;
  const float4* wr4 = (const float4*)wr;
  float e1 = 0.f, e2 = 0.f;
  #pragma unroll
  for (int q = 0; q < 16; ++q){
    float4 v = bp[q], a = wl4[q], b = wr4[q];
    e1 += v.x*a.x + v.y*a.y + v.z*a.z + v.w*a.w;
    e2 += v.x*b.x + v.y*b.y + v.z*b.z + v.w*b.w;
  }
  el[h*TOK + i] = e1;
  er[h*TOK + i] = e2;
}

// ---------- attention: flash-style, 64 i-rows per wg ----------
__global__ __launch_bounds__(256) void k_attn(const float* __restrict__ basic,
    const float* __restrict__ el, const float* __restrict__ er,
    const float* __restrict__ abp, float* __restrict__ hidden){
  __shared__ __align__(16) float tf[64*64];
  __shared__ __align__(16) float wb[64*64];   // wb[j][i]
  __shared__ float els[64];
  __shared__ float den4[4*64];
  __shared__ float dens[64];
  int h = blockIdx.y, i0 = blockIdx.x*64;
  int t = threadIdx.x;
  if (t < 64) els[t] = el[h*TOK + i0 + t] + abp[0];
  int iA = t & 63, jg = t >> 6;     // phase A: thread = (i, j-quarter)
  int dg = t & 15, ig = t >> 4;     // phase B: thread = (4 d's, 4 i's)
  float acc[16];
  #pragma unroll
  for (int q = 0; q < 16; ++q) acc[q] = 0.f;
  float dsum = 0.f;
  const float* erh = er + h*TOK;
  __syncthreads();
  float elsv = els[iA];
  for (int j0 = 0; j0 < TOK; j0 += 64){
    __syncthreads();  // protect tf/wb from previous iteration readers
    #pragma unroll
    for (int q = 0; q < 4; ++q){
      int f4 = q*256 + t, j = f4 >> 4, d4 = f4 & 15;
      *(float4*)&tf[j*64 + d4*4] = *(const float4*)&basic[(size_t)(j0+j)*HDIM + h*64 + d4*4];
    }
    #pragma unroll
    for (int q = 0; q < 16; ++q){
      int jj = jg*16 + q;
      float e = elsv + erh[j0 + jj];
      e = e > 0.f ? e : 0.01f*e;
      float wv = __expf(e);
      wb[jj*64 + iA] = wv;          // lanes i-consecutive: conflict-free
      dsum += wv;
    }
    __syncthreads();
    #pragma unroll 4
    for (int jj = 0; jj < 64; ++jj){
      float4 tv = *(const float4*)&tf[jj*64 + dg*4];  // 16 distinct b128 + broadcast: free
      float w0 = wb[jj*64 + ig*4 + 0];                 // wave-uniform: broadcast
      float w1 = wb[jj*64 + ig*4 + 1];
      float w2 = wb[jj*64 + ig*4 + 2];
      float w3 = wb[jj*64 + ig*4 + 3];
      acc[0] += w0*tv.x; acc[1] += w0*tv.y; acc[2] += w0*tv.z; acc[3] += w0*tv.w;
      acc[4] += w1*tv.x; acc[5] += w1*tv.y; acc[6] += w1*tv.z; acc[7] += w1*tv.w;
      acc[8] += w2*tv.x; acc[9] += w2*tv.y; acc[10]+= w2*tv.z; acc[11]+= w2*tv.w;
      acc[12]+= w3*tv.x; acc[13]+= w3*tv.y; acc[14]+= w3*tv.z; acc[15]+= w3*tv.w;
    }
  }
  den4[jg*64 + iA] = dsum;
  __syncthreads();
  if (t < 64) dens[t] = 1.f/(den4[t] + den4[64+t] + den4[128+t] + den4[192+t]);
  __syncthreads();
  #pragma unroll
  for (int ii = 0; ii < 4; ++ii){
    int i = ig*4 + ii;
    float rr = dens[i];
    size_t ob = (size_t)(i0+i)*HDIM + h*64 + dg*4;
    float4 bv = *(const float4*)&basic[ob];
    float4 ov;
    ov.x = bv.x + acc[ii*4+0]*rr;
    ov.y = bv.y + acc[ii*4+1]*rr;
    ov.z = bv.z + acc[ii*4+2]*rr;
    ov.w = bv.w + acc[ii*4+3]*rr;
    *(float4*)&hidden[ob] = ov;
  }
}

// ---------- bf16 MFMA GEMM: C(MrxN) = A(Mx512) @ B(Nx512)^T + bias ----------
// MODE 0: f32 row-major   MODE 1: bf16 row-major
// MODE 2: bf16 scattered for the scan: [row][sl][m][g] (inner = (hid>>3)*40 + (hid&7)*5 + gate)
template<int MODE>
__global__ __launch_bounds__(256) void k_gemm(const u16* __restrict__ A,
    const u16* __restrict__ B, void* __restrict__ C, const float* __restrict__ bias,
    int Mr, int Nn){
  __shared__ __align__(16) u16 Al[128*32];
  __shared__ __align__(16) u16 Bl[128*32];
  int tid = threadIdx.x;
  int wave = tid >> 6, lane = tid & 63;
  int m0 = blockIdx.y*128, n0 = blockIdx.x*128;
  int wm = wave >> 1, wn = wave & 1;
  f32x4 acc[4][4];
  #pragma unroll
  for (int a = 0; a < 4; ++a)
    #pragma unroll
    for (int b = 0; b < 4; ++b) acc[a][b] = (f32x4){0.f,0.f,0.f,0.f};
  int srow = lane >> 2;
  int kc = (lane & 3)*8;
  for (int k0 = 0; k0 < 512; k0 += 32){
    __syncthreads();
    #pragma unroll
    for (int n = 0; n < 2; ++n){
      int chunk = n*4 + wave;
      int row = chunk*16 + srow;
      const u16* ga = A + (size_t)(m0+row)*512 + k0 + kc;
      const u16* gb = B + (size_t)(n0+row)*512 + k0 + kc;
      __builtin_amdgcn_global_load_lds((const __attribute__((address_space(1))) void*)ga,
        (__attribute__((address_space(3))) void*)&Al[chunk*512], 16, 0, 0);
      __builtin_amdgcn_global_load_lds((const __attribute__((address_space(1))) void*)gb,
        (__attribute__((address_space(3))) void*)&Bl[chunk*512], 16, 0, 0);
    }
    __syncthreads();
    bf16x8 af[4], bfr[4];
    #pragma unroll
    for (int fm = 0; fm < 4; ++fm)
      af[fm] = *(const bf16x8*)&Al[(wm*64 + fm*16 + (lane&15))*32 + (lane>>4)*8];
    #pragma unroll
    for (int fn = 0; fn < 4; ++fn)
      bfr[fn] = *(const bf16x8*)&Bl[(wn*64 + fn*16 + (lane&15))*32 + (lane>>4)*8];
    #pragma unroll
    for (int fm = 0; fm < 4; ++fm)
      #pragma unroll
      for (int fn = 0; fn < 4; ++fn)
        acc[fm][fn] = __builtin_amdgcn_mfma_f32_16x16x32_bf16(af[fm], bfr[fn], acc[fm][fn], 0, 0, 0);
  }
  float* Cf = (float*)C;
  u16* Cb = (u16*)C;
  #pragma unroll
  for (int fn = 0; fn < 4; ++fn){
    int col = n0 + wn*64 + fn*16 + (lane & 15);
    float bv = bias ? bias[col] : 0.f;
    #pragma unroll
    for (int fm = 0; fm < 4; ++fm){
      #pragma unroll
      for (int rg = 0; rg < 4; ++rg){
        int m = m0 + wm*64 + fm*16 + (lane>>4)*4 + rg;   // C/D: col=lane&15, row=(lane>>4)*4+reg
        if (m < Mr){
          float v = acc[fm][fn][rg] + bv;
          if (MODE == 0) Cf[(size_t)m*Nn + col] = v;
          else if (MODE == 1) Cb[(size_t)m*Nn + col] = f2b(v);
          else {
            int g = col >> 9, hid = col & 511;
            int inner = (hid >> 3)*40 + (hid & 7)*5 + g;
            Cb[(size_t)m*GR + inner] = f2b(v);
          }
        }
      }
    }
  }
}

// ---------- the sequential scan, v2: 512 thr/wg, one poll word per thread,
// per-wave h-element ownership, shfl-only tail, single barrier per step ----------
__global__ __launch_bounds__(512, 2) void k_scan(
    const float* __restrict__ Wh_f, const float* __restrict__ Wh_b,
    const u16* __restrict__ gxs_f, const u16* __restrict__ gxs_b,  // [t][sl][m][g]
    const u16* __restrict__ px_f, const u16* __restrict__ px_b,
    u64* __restrict__ hx, float* __restrict__ out){
  int wg = blockIdx.x;
  int dir = wg & 1, sl = wg >> 1;   // 64 slices per direction
  int mb = sl*8;                    // this wg owns hidden indices [mb, mb+8)
  int tid = threadIdx.x;
  int wv = tid >> 6, lane = tid & 63;   // wave wv owns element mb+wv
  int g = lane >> 3, s8 = lane & 7;     // gate g (0..4 active), k-chunk s8
  const float* Wh = dir ? Wh_b : Wh_f;
  const u16* gxs = dir ? gxs_b : gxs_f;
  const u16* px  = dir ? px_b  : px_f;
  u64* hxd = hx + dir*1024;             // [2 parity][512]
  __shared__ __align__(16) float hls[2][8*68];  // 68-stride: 16B-aligned, conflict-free b128
  float wreg[64];
  if (g < 5){
    const float* wrow = Wh + (size_t)(g*512 + mb + wv)*512 + s8*64;
    #pragma unroll
    for (int k = 0; k < 64; ++k) wreg[k] = wrow[k];
  } else {
    #pragma unroll
    for (int k = 0; k < 64; ++k) wreg[k] = 0.f;
  }
  float c = 0.f;
  int myChunk = tid >> 6, myOff = tid & 63;
  for (int t = 0; t < TS; ++t){
    int trow = dir ? (4094 - t) : t;
    // prefetch gx (5 contiguous bf16 per wave) and px — independent of h, hidden under poll
    float gxv = 0.f, pxv = 0.f;
    if (g < 5 && s8 == 0) gxv = b2f(gxs[(size_t)trow*GR + sl*40 + wv*5 + g]);
    if (lane == 0)        pxv = b2f(px[(size_t)trow*HDIM + mb + wv]);
    // poll: one tagged word per thread, single round trip
    u64* src = hxd + (t & 1)*512;
    u64 v = __hip_atomic_load(&src[tid], __ATOMIC_RELAXED, __HIP_MEMORY_SCOPE_AGENT);
    while ((u32)(v >> 32) != (u32)t)
      v = __hip_atomic_load(&src[tid], __ATOMIC_RELAXED, __HIP_MEMORY_SCOPE_AGENT);
    float* hb = hls[t & 1];
    hb[myChunk*68 + myOff] = __uint_as_float((u32)v);   // 2 lanes/bank: free
    __syncthreads();
    // matvec slice: 64 MACs/lane, weights in VGPRs, h from LDS (conflict-free)
    float acc = 0.f;
    if (g < 5){
      const float4* hp4 = (const float4*)&hb[s8*68];
      #pragma unroll
      for (int q = 0; q < 16; ++q){
        float4 hv = hp4[q];
        acc += wreg[q*4+0]*hv.x + wreg[q*4+1]*hv.y + wreg[q*4+2]*hv.z + wreg[q*4+3]*hv.w;
      }
    }
    acc += __shfl_xor(acc, 1);
    acc += __shfl_xor(acc, 2);
    acc += __shfl_xor(acc, 4);
    // per-gate nonlinearity in parallel on the 5 s8==0 lanes
    float gv = acc + gxv;
    float sg = sigf(gv);
    float th = tanhfast(gv);
    float act = (g == 3) ? th : sg;
    // lane 0 gathers the 5 activations
    float ai = __shfl(act, 0);
    float ao = __shfl(act, 8);
    float af = __shfl(act, 16);
    float au = __shfl(act, 24);
    float ar = __shfl(act, 32);
    if (lane == 0){
      c = ai*au + af*c;
      float hh = ao*tanhfast(c);
      float hf = ar*hh + (1.f - ar)*pxv;
      int orow = dir ? (4095 - t) : (t + 1);
      out[(size_t)orow*1024 + dir*512 + mb + wv] = hf;
      u64 pv = (((u64)(u32)(t+1)) << 32) | (u64)__float_as_uint(hf);
      __hip_atomic_store(&hxd[((t+1) & 1)*512 + mb + wv], pv,
                         __ATOMIC_RELAXED, __HIP_MEMORY_SCOPE_AGENT);
    }
    // no second barrier: next step writes hls[(t+1)&1] (double-buffered)
  }
}

extern "C" void kernel_launch(void* const* d_in, const int* in_sizes, int n_in,
                              void* d_out, int out_size, void* d_ws, size_t ws_size,
                              hipStream_t stream){
  const float* features = (const float*)d_in[0];
  const float* Wr   = (const float*)d_in[1];
  const float* wl   = (const float*)d_in[2];
  const float* wr   = (const float*)d_in[3];
  const float* ab   = (const float*)d_in[4];
  const float* Wx_f = (const float*)d_in[5];
  const float* bx_f = (const float*)d_in[6];
  const float* Wh_f = (const float*)d_in[7];
  const float* bh_f = (const float*)d_in[8];
  const float* Px_f = (const float*)d_in[9];
  const float* pb_f = (const float*)d_in[10];
  const float* Wx_b = (const float*)d_in[11];
  const float* bx_b = (const float*)d_in[12];
  const float* Wh_b = (const float*)d_in[13];
  const float* bh_b = (const float*)d_in[14];
  const float* Px_b = (const float*)d_in[15];
  const float* pb_b = (const float*)d_in[16];
  float* out = (float*)d_out;

  size_t off = 0;
  auto alloc = [&](size_t b)->void*{ void* p = (char*)d_ws + off; off += (b + 255) & ~(size_t)255; return p; };
  u16* feat_b  = (u16*)alloc((size_t)TOK*HDIM*2);
  u16* Wr_b    = (u16*)alloc((size_t)HDIM*HDIM*2);
  u16* Wxf_b   = (u16*)alloc((size_t)GR*HDIM*2);
  u16* Wxb_b   = (u16*)alloc((size_t)GR*HDIM*2);
  u16* Pxf_b   = (u16*)alloc((size_t)HDIM*HDIM*2);
  u16* Pxb_b   = (u16*)alloc((size_t)HDIM*HDIM*2);
  float* bxh_f = (float*)alloc((size_t)GR*4);
  float* bxh_b = (float*)alloc((size_t)GR*4);
  float* basic = (float*)alloc((size_t)TOK*HDIM*4);
  float* el    = (float*)alloc((size_t)8*TOK*4);
  float* er    = (float*)alloc((size_t)8*TOK*4);
  float* hidden= (float*)alloc((size_t)TOK*HDIM*4);
  u16* child_b = (u16*)alloc((size_t)TOK*HDIM*2);
  u16* gxbf    = (u16*)alloc((size_t)TOK*GR*2);
  u16* gxbb    = (u16*)alloc((size_t)TOK*GR*2);
  u16* pxf     = (u16*)alloc((size_t)TOK*HDIM*2);
  u16* pxb     = (u16*)alloc((size_t)TOK*HDIM*2);
  u64* hx      = (u64*)alloc((size_t)2*2*512*8);

  auto cvt = [&](const float* src, u16* dst, int n){
    int nb = (n + 255)/256; if (nb > 2048) nb = 2048;
    k_f2b<<<nb, 256, 0, stream>>>(src, dst, n);
  };
  cvt(features, feat_b, TOK*HDIM);
  cvt(Wr, Wr_b, HDIM*HDIM);
  cvt(Wx_f, Wxf_b, GR*HDIM);
  cvt(Wx_b, Wxb_b, GR*HDIM);
  cvt(Px_f, Pxf_b, HDIM*HDIM);
  cvt(Px_b, Pxb_b, HDIM*HDIM);
  k_bias<<<10, 256, 0, stream>>>(bx_f, bh_f, bxh_f, GR);
  k_bias<<<10, 256, 0, stream>>>(bx_b, bh_b, bxh_b, GR);
  k_init<<<8, 256, 0, stream>>>(out, hx);

  k_gemm<0><<<dim3(4,32), 256, 0, stream>>>(feat_b, Wr_b, basic, nullptr, 4096, HDIM);
  k_eler<<<dim3(8,16), 256, 0, stream>>>(basic, wl, wr, el, er);
  k_attn<<<dim3(64,8), 256, 0, stream>>>(basic, el, er, ab, hidden);
  k_child<<<8192, 256, 0, stream>>>(hidden, child_b);

  k_gemm<2><<<dim3(20,32), 256, 0, stream>>>(child_b, Wxf_b, gxbf, bxh_f, TS, GR);
  k_gemm<2><<<dim3(20,32), 256, 0, stream>>>(child_b, Wxb_b, gxbb, bxh_b, TS, GR);
  k_gemm<1><<<dim3(4,32),  256, 0, stream>>>(child_b, Pxf_b, pxf, pb_f, TS, HDIM);
  k_gemm<1><<<dim3(4,32),  256, 0, stream>>>(child_b, Pxb_b, pxb, pb_b, TS, HDIM);

  k_scan<<<128, 512, 0, stream>>>(Wh_f, Wh_b, gxbf, gxbb, pxf, pxb, hx, out);
}